// Round 2
// baseline (1510.133 us; speedup 1.0000x reference)
//
#include <hip/hip_runtime.h>
#include <hip/hip_bf16.h>

// Problem constants (fixed by reference)
#define HD 256
#define NG 64
#define NNODES 10000
#define NEDGES 160000
#define MBLK 256
#define NTHREADS 1024

typedef __attribute__((ext_vector_type(8))) short short8;
typedef __attribute__((ext_vector_type(4))) float f32x4;

__device__ __forceinline__ unsigned int pkbf2(float a, float b) {
  __hip_bfloat162 h = __float22bfloat162_rn(float2{a, b});
  return *reinterpret_cast<unsigned int*>(&h);
}
__device__ __forceinline__ float silu_f(float x) {
  // x * 1/(1+exp(-x)) via exp2 + rcp (trans pipe), ~5 VALU ops
  float e = __builtin_amdgcn_exp2f(-1.442695041f * x);
  return x * __builtin_amdgcn_rcpf(1.0f + e);
}

// ---------------------------------------------------------------------------
// Prep: W1/W2/W3 (f32, [cin][cout]) -> Wt bf16 transposed [mat][cout][cin]
// ---------------------------------------------------------------------------
__global__ void prep_weights(const float* __restrict__ W1, const float* __restrict__ W2,
                             const float* __restrict__ W3, unsigned short* __restrict__ Wt) {
  int idx = blockIdx.x * blockDim.x + threadIdx.x;   // 3*65536 threads exactly
  int mat = idx >> 16;
  int rem = idx & 65535;
  int n = rem >> 8, k = rem & 255;                   // n=cout, k=cin
  const float* W = (mat == 0) ? W1 : (mat == 1) ? W2 : W3;
  __hip_bfloat16 h = __float2bfloat16(W[k * 256 + n]);
  Wt[idx] = *reinterpret_cast<unsigned short*>(&h);
}

// ---------------------------------------------------------------------------
// Fused mlp1 (3x GEMM 256x256 + SiLU) + segment-sum pooling via one-hot GEMM.
// Grid: 255 blocks = 3 heads x (5 node-blocks + 80 edge-blocks), 1024 threads.
// LDS: stage [256][256] bf16 (128KB, swizzled) + S^T [64][256] bf16 (32KB).
// 16 waves: 4 row-groups (64 rows) x 4 col-groups (64 couts); acc[4][4].
// Layers 0,1 use SWAPPED mfma operands (acc: lane=row, regs=4 consecutive couts)
// so silu write-back is packed b64, conflict-free. Layer 2 unswapped so the
// transposed h3^T write (for the pooling GEMM's B-frags) is packed b64.
// ---------------------------------------------------------------------------
__global__ __launch_bounds__(NTHREADS)
void fused_mlp1_pool(
    const float* __restrict__ nf0, const float* __restrict__ ef0,
    const int* __restrict__ ei0, const int* __restrict__ bt0,
    const float* __restrict__ nf1, const float* __restrict__ ef1,
    const int* __restrict__ ei1, const int* __restrict__ bt1,
    const float* __restrict__ nf2, const float* __restrict__ ef2,
    const int* __restrict__ ei2, const int* __restrict__ bt2,
    const float* __restrict__ b1, const float* __restrict__ b2,
    const float* __restrict__ b3,
    const unsigned short* __restrict__ Wt, float* __restrict__ pooled) {

  extern __shared__ char lds_raw[];
  char* stageB = lds_raw;            // 131072 B
  char* SB = lds_raw + 131072;       // 32768 B

  const int tid = threadIdx.x;
  const int wid = tid >> 6, lane = tid & 63;
  const int l15 = lane & 15, lhi = lane >> 4;
  const int wr = wid >> 2, wc = wid & 3;   // 4 row-groups x 4 col-groups
  const int wrow = wr * 64, wcol = wc * 64;

  const int bid = blockIdx.x;              // 0..254
  const int head = bid / 85;
  const int r85 = bid % 85;
  const int isEdge = (r85 >= 5) ? 1 : 0;
  const int lb = isEdge ? (r85 - 5) : r85;
  const int Bs = isEdge ? 80 : 5;
  const int rows = isEdge ? NEDGES : NNODES;
  const int ntiles = (rows + MBLK - 1) / MBLK;   // 625 or 40

  const float* X; const int* bt; const int* recv;
  if (head == 0)      { X = isEdge ? ef0 : nf0; bt = bt0; recv = ei0 + NEDGES; }
  else if (head == 1) { X = isEdge ? ef1 : nf1; bt = bt1; recv = ei1 + NEDGES; }
  else                { X = isEdge ? ef2 : nf2; bt = bt2; recv = ei2 + NEDGES; }
  float* pool = pooled + (head * 2 + isEdge) * (NG * HD);

  // Pooled accumulator in registers: [64 g][16 cols per wave], persists all tiles.
  f32x4 pacc[4];
  #pragma unroll
  for (int mt = 0; mt < 4; mt++) pacc[mt] = (f32x4){0.f, 0.f, 0.f, 0.f};

  // zero S once (re-zeroed at end of each tile, after P-GEMM reads)
  #pragma unroll
  for (int i = 0; i < 2; i++) ((int4*)SB)[tid + NTHREADS * i] = make_int4(0, 0, 0, 0);
  __syncthreads();

  for (int t = lb; t < ntiles; t += Bs) {
    const int rbase = t * MBLK;

    // ---- stage X (f32 -> bf16 via cvt_pk, swizzled) + scatter one-hot S ----
    #pragma unroll 4
    for (int i = 0; i < 16; i++) {
      int rr = wid + i * 16;
      int gr = rbase + rr; if (gr > rows - 1) gr = rows - 1;   // clamp pads
      f32x4 v = *(const f32x4*)(X + (long)gr * HD + lane * 4);
      uint2 pk = make_uint2(pkbf2(v.x, v.y), pkbf2(v.z, v.w));
      int byte = (rr * 512 + lane * 8) ^ ((rr & 7) << 4);
      *(uint2*)(stageB + byte) = pk;
    }
    if (tid < MBLK) {
      int gr = rbase + tid;
      if (gr < rows) {
        int g = isEdge ? bt[recv[gr]] : bt[gr];
        int byte = (g * 512 + tid * 2) ^ ((g & 7) << 4);
        *(unsigned short*)(SB + byte) = 0x3F80;   // bf16 1.0
      }
    }
    __syncthreads();

    // ---- 3 chained GEMMs: h = silu(h @ W + b), in-place in stage LDS ----
    #pragma unroll 1
    for (int layer = 0; layer < 3; layer++) {
      const unsigned short* Wl = Wt + layer * 65536;
      const float* bias = (layer == 0) ? b1 : (layer == 1) ? b2 : b3;

      f32x4 acc[4][4];   // wave tile: 64 rows x 64 couts
      if (layer < 2) {
        // swapped: acc[rt][ct] lane=row (l15), regs j = couts c0+j, c0=wcol+ct*16+lhi*4
        #pragma unroll
        for (int ct = 0; ct < 4; ct++) {
          f32x4 bv = *(const f32x4*)(bias + wcol + ct * 16 + lhi * 4);
          #pragma unroll
          for (int rt = 0; rt < 4; rt++) acc[rt][ct] = bv;
        }
      } else {
        // unswapped: lane=cout (l15), regs j = rows
        #pragma unroll
        for (int ct = 0; ct < 4; ct++) {
          float bv = bias[wcol + ct * 16 + l15];
          #pragma unroll
          for (int rt = 0; rt < 4; rt++) acc[rt][ct] = (f32x4){bv, bv, bv, bv};
        }
      }

      #pragma unroll 2
      for (int k = 0; k < 8; k++) {
        short8 wfrag[4];
        #pragma unroll
        for (int ct = 0; ct < 4; ct++)
          wfrag[ct] = *(const short8*)(Wl + (wcol + ct * 16 + l15) * 256 + k * 32 + lhi * 8);
        #pragma unroll
        for (int rt = 0; rt < 4; rt++) {
          int row = wrow + rt * 16 + l15;
          int byte = (row * 512 + k * 64 + lhi * 16) ^ ((row & 7) << 4);
          short8 xf = *(const short8*)(stageB + byte);
          if (layer < 2) {
            #pragma unroll
            for (int ct = 0; ct < 4; ct++)
              acc[rt][ct] = __builtin_amdgcn_mfma_f32_16x16x32_bf16(wfrag[ct], xf, acc[rt][ct], 0, 0, 0);
          } else {
            #pragma unroll
            for (int ct = 0; ct < 4; ct++)
              acc[rt][ct] = __builtin_amdgcn_mfma_f32_16x16x32_bf16(xf, wfrag[ct], acc[rt][ct], 0, 0, 0);
          }
        }
      }
      __syncthreads();   // all stage reads done before overwrite

      if (layer < 2) {
        // silu + packed b64 write, row-major (next GEMM's A). Conflict-free.
        #pragma unroll
        for (int rt = 0; rt < 4; rt++) {
          int row = wrow + rt * 16 + l15;
          #pragma unroll
          for (int ct = 0; ct < 4; ct++) {
            int c0 = wcol + ct * 16 + lhi * 4;
            f32x4 a = acc[rt][ct];
            uint2 pk = make_uint2(pkbf2(silu_f(a.x), silu_f(a.y)),
                                  pkbf2(silu_f(a.z), silu_f(a.w)));
            int byte = (row * 512 + c0 * 2) ^ ((row & 7) << 4);
            *(uint2*)(stageB + byte) = pk;
          }
        }
      } else {
        // last layer: write h3 TRANSPOSED [cout][row] (packed b64) for P-GEMM B-frags
        #pragma unroll
        for (int rt = 0; rt < 4; rt++) {
          int row0 = wrow + rt * 16 + lhi * 4;
          #pragma unroll
          for (int ct = 0; ct < 4; ct++) {
            int col = wcol + ct * 16 + l15;
            f32x4 a = acc[rt][ct];
            uint2 pk = make_uint2(pkbf2(silu_f(a.x), silu_f(a.y)),
                                  pkbf2(silu_f(a.z), silu_f(a.w)));
            int byte = (col * 512 + row0 * 2) ^ ((col & 7) << 4);
            *(uint2*)(stageB + byte) = pk;
          }
        }
      }
      __syncthreads();
    }

    // ---- P-GEMM: pacc += S^T(64x256) @ h3(256x256); wave owns cols [wid*16,+16) ----
    #pragma unroll 2
    for (int k = 0; k < 8; k++) {
      int col = wid * 16 + l15;
      int byteB = (col * 512 + k * 64 + lhi * 16) ^ ((col & 7) << 4);
      short8 bh = *(const short8*)(stageB + byteB);
      #pragma unroll
      for (int mt = 0; mt < 4; mt++) {
        int g = mt * 16 + l15;
        int byteA = (g * 512 + k * 64 + lhi * 16) ^ ((g & 7) << 4);
        short8 aS = *(const short8*)(SB + byteA);
        pacc[mt] = __builtin_amdgcn_mfma_f32_16x16x32_bf16(aS, bh, pacc[mt], 0, 0, 0);
      }
    }
    __syncthreads();       // P-GEMM reads of S done everywhere
    #pragma unroll
    for (int i = 0; i < 2; i++) ((int4*)SB)[tid + NTHREADS * i] = make_int4(0, 0, 0, 0);
    __syncthreads();       // S clean + stage free for next tile
  }

  // ---- flush pooled partials (once per block) ----
  #pragma unroll
  for (int mt = 0; mt < 4; mt++) {
    int col = wid * 16 + l15;
    #pragma unroll
    for (int j = 0; j < 4; j++) {
      int g = mt * 16 + lhi * 4 + j;
      unsafeAtomicAdd(&pool[g * HD + col], pacc[mt][j]);
    }
  }
}

// ---------------------------------------------------------------------------
// mlp2 on pooled (64 graphs) + combine lp - pk - lg. Block per (graph, head).
// ---------------------------------------------------------------------------
__global__ void mlp2_kernel(const float* __restrict__ pooled,
                            const float* __restrict__ V1, const float* __restrict__ c1,
                            const float* __restrict__ V2, const float* __restrict__ c2,
                            const float* __restrict__ V3, const float* __restrict__ c3,
                            float* __restrict__ out) {
  __shared__ float x[512];
  __shared__ float hb[256];
  __shared__ float wsum[4];
  const int g = blockIdx.x & 63, head = blockIdx.x >> 6, t = threadIdx.x;  // 256 thr

  x[t]       = pooled[(head * 2 + 0) * NG * HD + g * HD + t];
  x[t + 256] = pooled[(head * 2 + 1) * NG * HD + g * HD + t];
  __syncthreads();

  float a = c1[t];
  #pragma unroll 8
  for (int k = 0; k < 512; k++) a += x[k] * V1[k * HD + t];
  a = silu_f(a);
  hb[t] = a;
  __syncthreads();

  float b = c2[t];
  #pragma unroll 8
  for (int k = 0; k < 256; k++) b += hb[k] * V2[k * HD + t];
  b = silu_f(b);

  float p = b * V3[t];
  #pragma unroll
  for (int off = 32; off > 0; off >>= 1) p += __shfl_down(p, off, 64);
  if ((t & 63) == 0) wsum[t >> 6] = p;
  __syncthreads();
  if (t == 0) {
    float s = wsum[0] + wsum[1] + wsum[2] + wsum[3] + c3[0];
    unsafeAtomicAdd(&out[g], (head == 0) ? s : -s);
  }
}

// ---------------------------------------------------------------------------
extern "C" void kernel_launch(void* const* d_in, const int* in_sizes, int n_in,
                              void* d_out, int out_size, void* d_ws, size_t ws_size,
                              hipStream_t stream) {
  const float* nf0 = (const float*)d_in[0];
  const float* ef0 = (const float*)d_in[1];
  const int*   ei0 = (const int*)d_in[2];
  const int*   bt0 = (const int*)d_in[3];
  const float* nf1 = (const float*)d_in[4];
  const float* ef1 = (const float*)d_in[5];
  const int*   ei1 = (const int*)d_in[6];
  const int*   bt1 = (const int*)d_in[7];
  const float* nf2 = (const float*)d_in[8];
  const float* ef2 = (const float*)d_in[9];
  const int*   ei2 = (const int*)d_in[10];
  const int*   bt2 = (const int*)d_in[11];
  const float* W1 = (const float*)d_in[12]; const float* b1 = (const float*)d_in[13];
  const float* W2 = (const float*)d_in[14]; const float* b2 = (const float*)d_in[15];
  const float* W3 = (const float*)d_in[16]; const float* b3 = (const float*)d_in[17];
  const float* V1 = (const float*)d_in[18]; const float* c1 = (const float*)d_in[19];
  const float* V2 = (const float*)d_in[20]; const float* c2 = (const float*)d_in[21];
  const float* V3 = (const float*)d_in[22]; const float* c3 = (const float*)d_in[23];

  float* pooled = (float*)d_ws;                                   // 6*64*256 f32 = 384KB
  unsigned short* Wt = (unsigned short*)((char*)d_ws + 393216);   // 3*65536 bf16 = 384KB

  hipMemsetAsync(pooled, 0, 393216, stream);
  hipMemsetAsync(d_out, 0, out_size * sizeof(float), stream);
  prep_weights<<<768, 256, 0, stream>>>(W1, W2, W3, Wt);

  hipFuncSetAttribute((const void*)fused_mlp1_pool,
                      hipFuncAttributeMaxDynamicSharedMemorySize, 163840);
  fused_mlp1_pool<<<255, NTHREADS, 163840, stream>>>(
      nf0, ef0, ei0, bt0, nf1, ef1, ei1, bt1, nf2, ef2, ei2, bt2,
      b1, b2, b3, Wt, pooled);

  mlp2_kernel<<<192, 256, 0, stream>>>(pooled, V1, c1, V2, c2, V3, c3, (float*)d_out);
}